// Round 6
// baseline (306.892 us; speedup 1.0000x reference)
//
#include <hip/hip_runtime.h>
#include <hip/hip_bf16.h>

constexpr int kS   = 32;
constexpr int kB   = 256;
constexpr int kIN  = 1024;
constexpr int kOUT = 1024;
constexpr int BN   = 32;         // o-cols per block
constexpr int BK   = 32;         // k per MFMA tile
constexpr int CK   = 256;        // k per eps chunk (1 KB burst per row)
constexpr int NT   = kIN / BK;   // 32 tiles

typedef __bf16 v8bf __attribute__((ext_vector_type(8)));
typedef float  v4f  __attribute__((ext_vector_type(4)));

__device__ __forceinline__ float softplus_f(float x) {
    return fmaxf(x, 0.0f) + log1pf(expf(-fabsf(x)));
}
__device__ __forceinline__ unsigned int bfbits(float x) {
    __bf16 h = (__bf16)x;
    unsigned short u;
    __builtin_memcpy(&u, &h, 2);
    return (unsigned int)u;
}
__device__ __forceinline__ float asf(unsigned int u) {
    float f; __builtin_memcpy(&f, &u, 4); return f;
}

// pack (bf16(mu) low, bf16(softplus(rho)) high) into u32 per weight element
__global__ void sigma_pack(const float* __restrict__ mu, const float* __restrict__ rho,
                           uint4* __restrict__ ms) {
    int gid = blockIdx.x * blockDim.x + threadIdx.x;  // 4 elems/thread
    float4 m = reinterpret_cast<const float4*>(mu)[gid];
    float4 r = reinterpret_cast<const float4*>(rho)[gid];
    uint4 o;
    o.x = bfbits(m.x) | (bfbits(softplus_f(r.x)) << 16);
    o.y = bfbits(m.y) | (bfbits(softplus_f(r.y)) << 16);
    o.z = bfbits(m.z) | (bfbits(softplus_f(r.z)) << 16);
    o.w = bfbits(m.w) | (bfbits(softplus_f(r.w)) << 16);
    ms[gid] = o;
}

// cast X fp32 -> bf16 workspace, 8 elems/thread
__global__ void xcast_kernel(const float* __restrict__ X, __bf16* __restrict__ Xb) {
    size_t i = ((size_t)blockIdx.x * blockDim.x + threadIdx.x) * 8;
    float4 a = *reinterpret_cast<const float4*>(X + i);
    float4 b = *reinterpret_cast<const float4*>(X + i + 4);
    v8bf r;
    r[0] = (__bf16)a.x; r[1] = (__bf16)a.y; r[2] = (__bf16)a.z; r[3] = (__bf16)a.w;
    r[4] = (__bf16)b.x; r[5] = (__bf16)b.y; r[6] = (__bf16)b.z; r[7] = (__bf16)b.w;
    *reinterpret_cast<v8bf*>(Xb + i) = r;
}

// async 16B/lane global->LDS (no result VGPRs; lds dest = uniform base + lane*16)
#define GLDS16(g, l) __builtin_amdgcn_global_load_lds(                      \
    (const __attribute__((address_space(1))) void*)(g),                     \
    (__attribute__((address_space(3))) void*)(l), 16, 0, 0)

// v6: single-pass fused kernel = r0's 1 KB eps bursts + v4's counted-vmcnt
// GLDS ring (continuous issue, never drained mid-loop).
// Block = (s, M=256, N=32), 8 waves (wave = 32 rows x 32 cols). Rings:
//   eps fp32  [2][32 rows][256 k]  (staged per chunk,   4 GLDS16/wave, 1 KB rows)
//   ms  u32   [2][32 rows][128 k]  (staged per 1/2 chunk, 2 GLDS16/wave, L2-hot)
//   X   bf16  [3][256 rows][32 k]  (staged per tile, v4-verbatim, 2 GLDS16/wave)
// All LDS linear; swizzle achieved by XOR-permuted *global* source (m173) and
// matching XOR on the LDS read -> <=2-way bank aliasing (free). Fully unrolled
// 32-tile loop: every s_waitcnt vmcnt(N) is an exact issue count (8/4/2, 0 only
// at the final tile); lgkmcnt(0) before each raw s_barrier closes all ring
// reuse hazards. W = mu + sigma*eps built in-lane at the MFMA consume point.
__global__ __launch_bounds__(512, 2) void dv_main(
        const __bf16* __restrict__ Xb,          // [S][B][IN] bf16 workspace
        const unsigned int* __restrict__ MS,    // [OUT][IN] packed (mu,sigma)
        const float* __restrict__ Ew,           // [S][OUT][IN]
        const float* __restrict__ Bmu,          // [OUT]
        const float* __restrict__ Brho,         // [OUT]
        const float* __restrict__ Eb,           // [S][OUT]
        float* __restrict__ O)                  // [S][B][OUT]
{
    __shared__ __attribute__((aligned(16))) float        Ep[2][BN * CK];      // 64 KB
    __shared__ __attribute__((aligned(16))) unsigned int Mp[2][BN * (CK/2)];  // 32 KB
    __shared__ __attribute__((aligned(16))) __bf16       Xs[3][kB * BK];      // 48 KB

    const int tid = threadIdx.x, bb = blockIdx.x;
    const int xcd = bb & 7;
    const int jj  = bb >> 3;                   // 0..127
    const int s   = (xcd << 2) | (jj & 3);     // 4 s-values per XCD -> X L2-resident
    const int ot  = jj >> 2;                   // 0..31
    const int o_base = ot * BN;

    const int lane = tid & 63, wv = tid >> 6;  // wv 0..7
    const int lr = lane & 15, kg = lane >> 4;

    // ---- X staging (v4-verified quarter-rotation) ----
    const __bf16* Xbase = Xb + (size_t)s * kB * kIN;
    const int xrow = wv * 32 + (lane >> 2);
    const int xq0  = ((lane & 3) - (xrow >> 2)) & 3;
    const int xq1  = ((lane & 3) - ((xrow + 16) >> 2)) & 3;

    auto STAGE_X = [&](int t, int bf) {
        GLDS16(Xbase + (size_t)xrow * kIN + t * BK + xq0 * 8,
               &Xs[bf][(wv * 32) * BK]);
        GLDS16(Xbase + (size_t)(xrow + 16) * kIN + t * BK + xq1 * 8,
               &Xs[bf][(wv * 32 + 16) * BK]);
    };
    // ---- eps staging: wave covers rows wv*4..+3, one 1 KB row per GLDS16.
    // LDS linear granule l holds global granule l^(r&7) (pre-swizzled source).
    auto STAGE_E = [&](int c, int bf) {
        #pragma unroll
        for (int j = 0; j < 4; ++j) {
            int r = wv * 4 + j;
            GLDS16(Ew + ((size_t)s * kOUT + o_base + r) * kIN + c * CK
                       + ((lane ^ (r & 7)) << 2),
                   (char*)&Ep[bf][0] + r * 1024);
        }
    };
    // ---- ms staging: 2 rows (512 B each) per GLDS16, same XOR-swizzled source.
    auto STAGE_M = [&](int sub, int bf) {
        #pragma unroll
        for (int j = 0; j < 2; ++j) {
            int r0 = j * 16 + wv * 2;
            int r  = r0 + (lane >> 5);
            GLDS16(MS + (size_t)(o_base + r) * kIN + sub * 128
                      + (((lane & 31) ^ (r & 7)) << 2),
                   (char*)&Mp[bf][0] + r0 * 512);
        }
    };

    v4f acc[2][2] = {};

    // ---- prologue: eps[0](4), ms[0](2), X[0](2), X[1](2) ----
    STAGE_E(0, 0);
    STAGE_M(0, 0);
    STAGE_X(0, 0);
    STAGE_X(1, 1);

    #pragma unroll
    for (int T = 0; T < NT; ++T) {
        // exact counted wait: N = issues of previous tile (prologue for T=0)
        if (T == 1 || T == 9 || T == 17)
            asm volatile("s_waitcnt vmcnt(8) lgkmcnt(0)" ::: "memory");
        else if (T == 5 || T == 13 || T == 21 || T == 25)
            asm volatile("s_waitcnt vmcnt(4) lgkmcnt(0)" ::: "memory");
        else if (T == 31)
            asm volatile("s_waitcnt vmcnt(0) lgkmcnt(0)" ::: "memory");
        else
            asm volatile("s_waitcnt vmcnt(2) lgkmcnt(0)" ::: "memory");
        __builtin_amdgcn_s_barrier();          // raw: no compiler vmcnt(0) drain

        // ---- issue-ahead (order matters for the counts: eps, ms, X) ----
        if ((T & 7) == 0 && T < 24) STAGE_E(T / 8 + 1, (T / 8 + 1) & 1);
        if ((T & 3) == 0 && T < 28) STAGE_M(T / 4 + 1, (T / 4 + 1) & 1);
        if (T < 30)                 STAGE_X(T + 2, (T + 2) % 3);

        // ---- A frags (v4-verified layout) ----
        const int bf = T % 3;
        v8bf a[2];
        #pragma unroll
        for (int mf = 0; mf < 2; ++mf) {
            int row = wv * 32 + mf * 16 + lr;
            int ql  = (kg + (row >> 2)) & 3;
            a[mf] = *reinterpret_cast<const v8bf*>(&Xs[bf][row * BK + ql * 8]);
        }

        // ---- B frags: swizzled eps (fp32) + ms (packed), W built in-lane ----
        const char* eb = (const char*)&Ep[(T >> 3) & 1][0];
        const char* mb = (const char*)&Mp[(T >> 2) & 1][0];
        v8bf b[2];
        #pragma unroll
        for (int nf = 0; nf < 2; ++nf) {
            int r  = nf * 16 + lr;
            int sw = r & 7;
            int g0  = (T & 7) * 8 + kg * 2;    // eps granule (16 B) index, even
            int g0m = (T & 3) * 8 + kg * 2;    // ms granule index, even
            float4 e0 = *reinterpret_cast<const float4*>(eb + r * 1024 + ((g0 ^ sw) << 4));
            float4 e1 = *reinterpret_cast<const float4*>(eb + r * 1024 + (((g0 + 1) ^ sw) << 4));
            uint4  p0 = *reinterpret_cast<const uint4*>(mb + r * 512 + ((g0m ^ sw) << 4));
            uint4  p1 = *reinterpret_cast<const uint4*>(mb + r * 512 + (((g0m + 1) ^ sw) << 4));
            b[nf][0] = (__bf16)fmaf(asf(p0.x & 0xffff0000u), e0.x, asf(p0.x << 16));
            b[nf][1] = (__bf16)fmaf(asf(p0.y & 0xffff0000u), e0.y, asf(p0.y << 16));
            b[nf][2] = (__bf16)fmaf(asf(p0.z & 0xffff0000u), e0.z, asf(p0.z << 16));
            b[nf][3] = (__bf16)fmaf(asf(p0.w & 0xffff0000u), e0.w, asf(p0.w << 16));
            b[nf][4] = (__bf16)fmaf(asf(p1.x & 0xffff0000u), e1.x, asf(p1.x << 16));
            b[nf][5] = (__bf16)fmaf(asf(p1.y & 0xffff0000u), e1.y, asf(p1.y << 16));
            b[nf][6] = (__bf16)fmaf(asf(p1.z & 0xffff0000u), e1.z, asf(p1.z << 16));
            b[nf][7] = (__bf16)fmaf(asf(p1.w & 0xffff0000u), e1.w, asf(p1.w << 16));
        }

        // ---- 4 MFMAs ----
        #pragma unroll
        for (int mf = 0; mf < 2; ++mf)
            #pragma unroll
            for (int nf = 0; nf < 2; ++nf)
                acc[mf][nf] = __builtin_amdgcn_mfma_f32_16x16x32_bf16(
                    a[mf], b[nf], acc[mf][nf], 0, 0, 0);
    }

    // ---- epilogue: inline-sampled bias + nontemporal full-line stores ----
    float bias[2];
    #pragma unroll
    for (int nf = 0; nf < 2; ++nf) {
        int o = o_base + nf * 16 + lr;
        bias[nf] = fmaf(softplus_f(Brho[o]), Eb[(size_t)s * kOUT + o], Bmu[o]);
    }
    #pragma unroll
    for (int mf = 0; mf < 2; ++mf) {
        #pragma unroll
        for (int rr = 0; rr < 4; ++rr) {
            int mrow = wv * 32 + mf * 16 + kg * 4 + rr;   // C/D: row=(lane>>4)*4+reg
            float* orow = O + ((size_t)s * kB + mrow) * kOUT + o_base;
            #pragma unroll
            for (int nf = 0; nf < 2; ++nf)
                __builtin_nontemporal_store(acc[mf][nf][rr] + bias[nf],
                                            orow + nf * 16 + lr);  // col = lane&15
        }
    }
}

// safety-net fallback (workspace too small — not expected)
__global__ void dv_naive(const float* __restrict__ X, const float* __restrict__ Wmu,
                         const float* __restrict__ Wrho, const float* __restrict__ Bmu,
                         const float* __restrict__ Brho, const float* __restrict__ Ew,
                         const float* __restrict__ Eb, float* __restrict__ O) {
    size_t gid = (size_t)blockIdx.x * blockDim.x + threadIdx.x;  // s*B*OUT
    int o = gid % kOUT;
    int b = (gid / kOUT) % kB;
    int s = gid / ((size_t)kOUT * kB);
    const float* x = X + ((size_t)s * kB + b) * kIN;
    const float* e = Ew + ((size_t)s * kOUT + o) * kIN;
    const float* wm = Wmu + (size_t)o * kIN;
    const float* wr = Wrho + (size_t)o * kIN;
    float acc = 0.f;
    for (int k = 0; k < kIN; ++k)
        acc += x[k] * fmaf(softplus_f(wr[k]), e[k], wm[k]);
    O[gid] = acc + fmaf(softplus_f(Brho[o]), Eb[(size_t)s * kOUT + o], Bmu[o]);
}

extern "C" void kernel_launch(void* const* d_in, const int* in_sizes, int n_in,
                              void* d_out, int out_size, void* d_ws, size_t ws_size,
                              hipStream_t stream) {
    const float* input = (const float*)d_in[0];
    const float* w_mu  = (const float*)d_in[1];
    const float* w_rho = (const float*)d_in[2];
    const float* b_mu  = (const float*)d_in[3];
    const float* b_rho = (const float*)d_in[4];
    const float* eps_w = (const float*)d_in[5];
    const float* eps_b = (const float*)d_in[6];
    float* out = (float*)d_out;

    const size_t ms_bytes  = (size_t)kOUT * kIN * 4;                 //  4 MB
    const size_t xbf_bytes = (size_t)kS * kB * kIN * sizeof(__bf16); // 16 MB

    if (ws_size < ms_bytes + xbf_bytes) {
        dv_naive<<<dim3((size_t)kS * kB * kOUT / 256), 256, 0, stream>>>(
            input, w_mu, w_rho, b_mu, b_rho, eps_w, eps_b, out);
        return;
    }

    unsigned int* ms = (unsigned int*)d_ws;
    __bf16* xbf = (__bf16*)((char*)d_ws + ms_bytes);

    sigma_pack<<<dim3((kOUT * kIN) / (256 * 4)), 256, 0, stream>>>(w_mu, w_rho, (uint4*)ms);
    xcast_kernel<<<dim3((size_t)kS * kB * kIN / (256 * 8)), 256, 0, stream>>>(input, xbf);

    dim3 grid(kS * (kOUT / BN));   // 1024 blocks, XCD-swizzled (s pinned per XCD)
    dv_main<<<grid, 512, 0, stream>>>(xbf, ms, eps_w, b_mu, b_rho, eps_b, out);
}